// Round 10
// baseline (4152.207 us; speedup 1.0000x reference)
//
#include <hip/hip_runtime.h>
#include <math.h>

#define NQ 12
#define LAYERS 8
#define BATCH 4096

// R9 post-mortem: spill eliminated (WRITE=output exactly) but dur 757us,
// VALUBusy 67%, occupancy ~21% (4 waves/SIMD at VGPR=128). This round:
// cross the 64-VGPR occupancy cliff (m69: waves halve at 64/128/256).
//
// FOUR waves per batch element (block=256), 16 amps/lane = 32 state VGPRs.
// Amplitude flat index i (bit11..bit0): r3 r2 r1 r0 | w1 w0 | l5..l0
//   wires 0..3  -> reg bits   (in-register 2x2 gates)
//   wires 4..5  -> wave bits  (gates via 16KB LDS exchange)
//   wires 6..11 -> lane bits  (ds_swizzle butterfly gates, masks immediate)
// CNOT ring: (0,1)(1,2)(2,3) = compile-time reg swaps; (3,4) = odd-reg LDS
// exchange with wave lwv^2; (4,5) = LOGICAL WAVE LABEL swap (lwv: 2<->3,
// zero data movement -- all LDS slots/partners indexed by lwv); (5,6)
// merged into the sigma shuffle pass (^32 where lwv&1); (6,7)..(10,11) =
// sigma(l)=l^((l>>1)&31); (11,0) = odd lanes swap r <-> r|8 (cndmask).
//
// amdgpu_waves_per_eu(8,8) pins the <=64-VGPR budget -> 8 waves/SIMD.
//
// MODE 0: d_out = float[B*4096] (real parts; harness casts complex64->f32).
// MODE 1: d_out = float2[B*4096] interleaved.
template <int MODE>
__global__ __attribute__((amdgpu_waves_per_eu(8, 8))) __launch_bounds__(256)
void qsim_kernel(const float* __restrict__ x,
                 const float* __restrict__ input_params,
                 const float* __restrict__ weights,
                 float* __restrict__ out, long long out_elems) {
  const int b = blockIdx.x;
  const int tid = threadIdx.x;
  const int lane = tid & 63;
  int lwv = tid >> 6;                 // logical wave id, starts = physical

  __shared__ float2 xch[4][8][64];    // 16 KB, lane-contiguous: conflict-free

  float sr[16], si[16];
#pragma unroll
  for (int r = 0; r < 16; ++r) { sr[r] = 0.f; si[r] = 0.f; }
  sr[0] = (tid == 0) ? 1.f : 0.f;

  const int sigma = lane ^ ((lane >> 1) & 31);

  const float* xb = x + b * (NQ * LAYERS);

#pragma unroll 1
  for (int l = 0; l < LAYERS; ++l) {
    // --- fused gate per wire: lane w (w<12) computes U_w = Rot_w * RY_w ---
    // U = [[g, -conj(h)], [h, conj(g)]]  (identical in all 4 waves)
    float gr, gi, hr, hi;
    {
      const int wi = (lane < NQ) ? lane : (NQ - 1);
      const int idx = l * NQ + wi;
      const float a = input_params[idx] * xb[idx];
      float sa, ca; __sincosf(0.5f * a, &sa, &ca);
      const float phi = weights[idx * 3 + 0];
      const float th  = weights[idx * 3 + 1];
      const float om  = weights[idx * 3 + 2];
      float st, ct;    __sincosf(0.5f * th, &st, &ct);
      float spp, cpp_; __sincosf(0.5f * (phi + om), &spp, &cpp_);
      float smm, cmm;  __sincosf(0.5f * (phi - om), &smm, &cmm);
      const float ar = ct * cpp_, ai = -ct * spp;
      const float br = st * cmm,  bi = -st * smm;
      gr = ar * ca - br * sa;
      gi = ai * ca + bi * sa;
      hr = br * ca + ar * sa;
      hi = bi * ca - ai * sa;
    }

    // --- reg-bit gates: wires 0..3, masks 8,4,2,1 (all static) ---
#pragma unroll
    for (int w = 0; w < 4; ++w) {
      const float Gr = __shfl(gr, w), Gi = __shfl(gi, w);
      const float Hr = __shfl(hr, w), Hi = __shfl(hi, w);
      const int m = 8 >> w;
#pragma unroll
      for (int r0 = 0; r0 < 16; ++r0) {
        if (r0 & m) continue;
        const int r1 = r0 | m;
        const float s0r = sr[r0], s0i = si[r0];
        const float s1r = sr[r1], s1i = si[r1];
        sr[r0] = Gr * s0r - Gi * s0i - Hr * s1r - Hi * s1i;
        si[r0] = Gr * s0i + Gi * s0r + Hi * s1r - Hr * s1i;
        sr[r1] = Hr * s0r - Hi * s0i + Gr * s1r + Gi * s1i;
        si[r1] = Hr * s0i + Hi * s0r + Gr * s1i - Gi * s1r;
      }
    }

    // --- wave-bit gates: wire4 (partner lwv^2, sel bit1), wire5 (lwv^1, bit0)
#pragma unroll
    for (int w = 4; w <= 5; ++w) {
      const float Gr = __shfl(gr, w), Gi = __shfl(gi, w);
      const float Hr = __shfl(hr, w), Hi = __shfl(hi, w);
      const int pm = (w == 4) ? 2 : 1;
      const int bset = (w == 4) ? ((lwv >> 1) & 1) : (lwv & 1);
      const float Dr  = Gr;
      const float Di  = bset ? -Gi : Gi;
      const float Or_ = bset ?  Hr : -Hr;
      const float Oi  = Hi;
#pragma unroll
      for (int c = 0; c < 2; ++c) {
#pragma unroll
        for (int k = 0; k < 8; ++k)
          xch[lwv][k][lane] = make_float2(sr[c * 8 + k], si[c * 8 + k]);
        __syncthreads();
#pragma unroll
        for (int k = 0; k < 8; ++k) {
          const float2 p = xch[lwv ^ pm][k][lane];
          const int r = c * 8 + k;
          const float mr = sr[r], mi = si[r];
          sr[r] = Dr * mr - Di * mi + Or_ * p.x - Oi * p.y;
          si[r] = Dr * mi + Di * mr + Or_ * p.y + Oi * p.x;
        }
        __syncthreads();
      }
    }

    // --- lane-bit gates: wires 6..11, fully unrolled (masks immediate) ---
#pragma unroll
    for (int w = 6; w < 12; ++w) {
      const float Gr = __shfl(gr, w), Gi = __shfl(gi, w);
      const float Hr = __shfl(hr, w), Hi = __shfl(hi, w);
      const int lb = 11 - w;
      const int mask = 1 << lb;
      const int bset = (lane >> lb) & 1;
      const float Dr  = Gr;
      const float Di  = bset ? -Gi : Gi;
      const float Or_ = bset ?  Hr : -Hr;
      const float Oi  = Hi;
#pragma unroll
      for (int r = 0; r < 16; ++r) {
        const float pr = __shfl_xor(sr[r], mask);
        const float pi = __shfl_xor(si[r], mask);
        const float mr = sr[r], mi = si[r];
        sr[r] = Dr * mr - Di * mi + Or_ * pr - Oi * pi;
        si[r] = Dr * mi + Di * mr + Or_ * pi + Oi * pr;
      }
    }

    // --- CNOT ring, order (0,1)..(11,0) ---
    // (0,1)(1,2)(2,3): compile-time reg swaps
#pragma unroll
    for (int w = 0; w < 3; ++w) {
      const int cm = 8 >> w, tm = cm >> 1;
#pragma unroll
      for (int r = 0; r < 16; ++r) {
        if ((r & cm) && !(r & tm)) {
          const int p = r | tm;
          float t;
          t = sr[r]; sr[r] = sr[p]; sr[p] = t;
          t = si[r]; si[r] = si[p]; si[p] = t;
        }
      }
    }
    // (3,4): control r0 -> odd regs exchange with logical wave lwv^2
#pragma unroll
    for (int k = 0; k < 8; ++k)
      xch[lwv][k][lane] = make_float2(sr[2 * k + 1], si[2 * k + 1]);
    __syncthreads();
#pragma unroll
    for (int k = 0; k < 8; ++k) {
      const float2 p = xch[lwv ^ 2][k][lane];
      sr[2 * k + 1] = p.x; si[2 * k + 1] = p.y;
    }
    __syncthreads();
    // (4,5): control w1, target w0 -> pure logical relabel, no data motion
    if (lwv & 2) lwv ^= 1;
    // (5,6)+(6,7)..(10,11): single shuffle pass, wave-uniform source
    {
      const int src = (lwv & 1) ? (sigma ^ 32) : sigma;
#pragma unroll
      for (int r = 0; r < 16; ++r) {
        sr[r] = __shfl(sr[r], src);
        si[r] = __shfl(si[r], src);
      }
    }
    // (11,0): control l0, target r3 -> odd lanes swap r <-> r|8
    {
      const bool odd = (lane & 1) != 0;
#pragma unroll
      for (int r = 0; r < 8; ++r) {
        const float a0 = sr[r], b0 = sr[r + 8];
        sr[r]     = odd ? b0 : a0;
        sr[r + 8] = odd ? a0 : b0;
        const float a1 = si[r], b1 = si[r + 8];
        si[r]     = odd ? b1 : a1;
        si[r + 8] = odd ? a1 : b1;
      }
    }
  }

  // Store: idx = b*4096 + (r<<8) + (lwv<<6) + lane -- coalesced 256B per
  // wave per r. Bounds-guarded.
  const long long base = ((long long)b << NQ) + (lwv << 6) + lane;
  if (MODE == 0) {
#pragma unroll
    for (int r = 0; r < 16; ++r) {
      const long long idx = base + ((long long)r << 8);
      if (idx < out_elems) out[idx] = sr[r];
    }
  } else {
    float2* ob = (float2*)out;
#pragma unroll
    for (int r = 0; r < 16; ++r) {
      const long long idx = base + ((long long)r << 8);
      if (2 * idx + 1 < out_elems) ob[idx] = make_float2(sr[r], si[r]);
    }
  }
}

extern "C" void kernel_launch(void* const* d_in, const int* in_sizes, int n_in,
                              void* d_out, int out_size, void* d_ws, size_t ws_size,
                              hipStream_t stream) {
  const float* x  = (const float*)d_in[0];
  const float* ip = (const float*)d_in[1];
  const float* w  = (const float*)d_in[2];
  float* out = (float*)d_out;
  (void)in_sizes; (void)n_in; (void)d_ws; (void)ws_size;
  const long long total = (long long)BATCH << NQ;   // 16,777,216 amplitudes
  if ((long long)out_size == 2 * total) {
    qsim_kernel<1><<<BATCH, 256, 0, stream>>>(x, ip, w, out, (long long)out_size);
  } else {
    qsim_kernel<0><<<BATCH, 256, 0, stream>>>(x, ip, w, out, (long long)out_size);
  }
}

// Round 11
// 586.644 us; speedup vs baseline: 7.0779x; 7.0779x over previous
//
#include <hip/hip_runtime.h>
#include <math.h>

#define NQ 12
#define LAYERS 8
#define BATCH 4096

// R10 post-mortem: waves_per_eu(8,8) -> VGPR=32, 16.8GB spill, 4152us.
// Allocator rule learned: budgets can only be lowered, never raised; the
// only safe point is a live set that fits 128 VGPR naturally.
//
// This round: 3-phase LDS-transpose structure. Block=256 (4 waves) per
// batch element, 16 amps/lane (32 state VGPRs). Per layer, three layouts
// (cyclic wire rotation by 4) put each group of 4 wires into REGISTER
// bits, so ALL 12 1q gates are in-register 2x2s (zero shuffles), ring
// CNOTs are register renames, and the 3 cross-phase CNOTs are identical
// cndmask swaps. 3 LDS transposes/layer (96 DS ops vs ~550 shuffle DS in
// the R9 structure).
//
// Layouts (amp bit 11..0):
//   A: [w0 w1 w2 w3 | w4 ... w11]   regs=w0-3, T=[w4..w11]
//   B: [w4 w5 w6 w7 | w8..w11 w0..w3]
//   C: [w8 w9 w10 w11 | w0 ... w7]
// Transpose (same formula all 3): write lds[swz((r<<8)|tid)], read
// lds[swz((t4<<8)|(r<<4)|th)], swz(i) = i ^ ((i>>8)&15)*0x11 (full-BW).
//
// MODE 0: d_out = float[B*4096] (real parts; harness casts complex64->f32).
// MODE 1: d_out = float2[B*4096] interleaved.
template <int MODE>
__global__ __launch_bounds__(256)
void qsim_kernel(const float* __restrict__ x,
                 const float* __restrict__ input_params,
                 const float* __restrict__ weights,
                 float* __restrict__ out, long long out_elems) {
  const int b = blockIdx.x;
  const int tid = threadIdx.x;        // 0..255
  const int lane = tid & 63;
  const int t4 = tid & 15;
  const int th = tid >> 4;

  __shared__ float2 lds[4096];        // 32 KB

  float sr[16], si[16];
#pragma unroll
  for (int r = 0; r < 16; ++r) { sr[r] = 0.f; si[r] = 0.f; }
  sr[0] = (tid == 0) ? 1.f : 0.f;     // amp 0 lives at thread 0, reg 0 (layout A)

  const float* xb = x + b * (NQ * LAYERS);

  float gr, gi, hr, hi;               // per-lane gate coefs (lane w = wire w)

  // --- helpers ---
  auto cnotX = [&]() {                // control = tid bit0, target = reg bit3
    const bool odd = (tid & 1) != 0;
#pragma unroll
    for (int r = 0; r < 8; ++r) {
      const float a0 = sr[r], b0 = sr[r + 8];
      sr[r]     = odd ? b0 : a0;
      sr[r + 8] = odd ? a0 : b0;
      const float a1 = si[r], b1 = si[r + 8];
      si[r]     = odd ? b1 : a1;
      si[r + 8] = odd ? a1 : b1;
    }
  };
  auto gate = [&](int wl, int m) {    // broadcast coefs from lane wl, reg mask m
    const float Gr = __shfl(gr, wl), Gi = __shfl(gi, wl);
    const float Hr = __shfl(hr, wl), Hi = __shfl(hi, wl);
#pragma unroll
    for (int r0 = 0; r0 < 16; ++r0) {
      if (r0 & m) continue;           // compile-time skip
      const int r1 = r0 | m;
      const float s0r = sr[r0], s0i = si[r0];
      const float s1r = sr[r1], s1i = si[r1];
      // new0 = g*s0 - conj(h)*s1 ; new1 = h*s0 + conj(g)*s1
      sr[r0] = Gr * s0r - Gi * s0i - Hr * s1r - Hi * s1i;
      si[r0] = Gr * s0i + Gi * s0r + Hi * s1r - Hr * s1i;
      sr[r1] = Hr * s0r - Hi * s0i + Gr * s1r + Gi * s1i;
      si[r1] = Hr * s0i + Hi * s0r + Gr * s1i - Gi * s1r;
    }
  };
  auto renames = [&]() {              // CNOTs (a,a+1)(a+1,a+2)(a+2,a+3) in-regs
#pragma unroll
    for (int w = 0; w < 3; ++w) {
      const int cm = 8 >> w, tm = cm >> 1;
#pragma unroll
      for (int r = 0; r < 16; ++r) {
        if ((r & cm) && !(r & tm)) {
          const int p = r | tm;
          float t;
          t = sr[r]; sr[r] = sr[p]; sr[p] = t;
          t = si[r]; si[r] = si[p]; si[p] = t;
        }
      }
    }
  };
  auto transpose = [&]() {
#pragma unroll
    for (int r = 0; r < 16; ++r)
      lds[(r << 8) | (tid ^ (r * 0x11))] = make_float2(sr[r], si[r]);
    __syncthreads();
    const int rb = (t4 << 8) | (t4 << 4) | (th ^ t4);
#pragma unroll
    for (int r = 0; r < 16; ++r) {
      const float2 v = lds[rb ^ (r << 4)];
      sr[r] = v.x; si[r] = v.y;
    }
    __syncthreads();
  };

#pragma unroll 1
  for (int l = 0; l < LAYERS; ++l) {
    // --- fused gate per wire: lane w (w<12) computes U_w = Rot_w * RY_w ---
    // U = [[g, -conj(h)], [h, conj(g)]]  (identical in all 4 waves)
    {
      const int wi = (lane < NQ) ? lane : (NQ - 1);
      const int idx = l * NQ + wi;
      const float a = input_params[idx] * xb[idx];
      float sa, ca; __sincosf(0.5f * a, &sa, &ca);
      const float phi = weights[idx * 3 + 0];
      const float thw = weights[idx * 3 + 1];
      const float om  = weights[idx * 3 + 2];
      float st, ct;    __sincosf(0.5f * thw, &st, &ct);
      float spp, cpp_; __sincosf(0.5f * (phi + om), &spp, &cpp_);
      float smm, cmm;  __sincosf(0.5f * (phi - om), &smm, &cmm);
      const float ar = ct * cpp_, ai = -ct * spp;
      const float br = st * cmm,  bi = -st * smm;
      gr = ar * ca - br * sa;
      gi = ai * ca + bi * sa;
      hr = br * ca + ar * sa;
      hi = bi * ca - ai * sa;
    }

    // Phase A (regs = w0..w3): CNOT(11,0) of prev layer, then U0..U3, ring
    if (l > 0) cnotX();
    gate(0, 8); gate(1, 4); gate(2, 2); gate(3, 1);
    renames();                        // CNOT(0,1)(1,2)(2,3)
    transpose();                      // -> layout B

    // Phase B (regs = w4..w7): U4, CNOT(3,4), U5..U7, ring
    gate(4, 8);
    cnotX();                          // CNOT(3,4)
    gate(5, 4); gate(6, 2); gate(7, 1);
    renames();                        // CNOT(4,5)(5,6)(6,7)
    transpose();                      // -> layout C

    // Phase C (regs = w8..w11): U8, CNOT(7,8), U9..U11, ring
    gate(8, 8);
    cnotX();                          // CNOT(7,8)
    gate(9, 4); gate(10, 2); gate(11, 1);
    renames();                        // CNOT(8,9)(9,10)(10,11)
    transpose();                      // -> layout A
  }

  // Final CNOT(11,0) of the last layer (layout A), then store.
  cnotX();

  // Store: amp = (r<<8) | tid -- reference flat order; fully coalesced.
  const long long base = ((long long)b << NQ) + tid;
  if (MODE == 0) {
#pragma unroll
    for (int r = 0; r < 16; ++r) {
      const long long idx = base + (r << 8);
      if (idx < out_elems) out[idx] = sr[r];
    }
  } else {
    float2* ob = (float2*)out;
#pragma unroll
    for (int r = 0; r < 16; ++r) {
      const long long idx = base + (r << 8);
      if (2 * idx + 1 < out_elems) ob[idx] = make_float2(sr[r], si[r]);
    }
  }
}

extern "C" void kernel_launch(void* const* d_in, const int* in_sizes, int n_in,
                              void* d_out, int out_size, void* d_ws, size_t ws_size,
                              hipStream_t stream) {
  const float* x  = (const float*)d_in[0];
  const float* ip = (const float*)d_in[1];
  const float* w  = (const float*)d_in[2];
  float* out = (float*)d_out;
  (void)in_sizes; (void)n_in; (void)d_ws; (void)ws_size;
  const long long total = (long long)BATCH << NQ;   // 16,777,216 amplitudes
  if ((long long)out_size == 2 * total) {
    qsim_kernel<1><<<BATCH, 256, 0, stream>>>(x, ip, w, out, (long long)out_size);
  } else {
    qsim_kernel<0><<<BATCH, 256, 0, stream>>>(x, ip, w, out, (long long)out_size);
  }
}

// Round 13
// 339.039 us; speedup vs baseline: 12.2470x; 1.7303x over previous
//
#include <hip/hip_runtime.h>
#include <math.h>

#define NQ 12
#define LAYERS 8
#define BATCH 4096

typedef float f2 __attribute__((ext_vector_type(2)));
typedef float f4 __attribute__((ext_vector_type(4)));

// R11 post-mortem: VALU-issue-bound (VALUBusy 84%, dur 617us, zero spill,
// zero bank conflicts). This round: halve the gate arithmetic with CDNA
// packed fp32 (VOP3P v_pk_fma_f32). State = packed (re,im) f2 pairs; the
// 2-amp gate update is 8 packed insts (op_sel broadcasts/swaps, neg_lo/hi
// folds signs). Gate coefs go through a 12-entry LDS table (1 ds_read_b128
// per gate) instead of 4 shfl broadcasts.
//
// Structure (verified R11): block=256/element, 16 amps/lane; 3 phases per
// layer with LDS transposes rotating wires into register bits; ring CNOTs
// are register renames; phase-boundary CNOTs are cndmask swaps.
//   out0 = g*s0 - conj(h)*s1 ; out1 = h*s0 + conj(g)*s1
// packed: T=(out0.re,out0.im): pk_mul(G.lo,P0) ; pk_fma(G.hi,P0.swap,neg_lo)
//         pk_fma(H.lo.neg,P1) ; pk_fma(H.hi,P1.swap,neg_lo)
//         U=(out1.re,out1.im): pk_mul(H.lo,P0) ; pk_fma(H.hi,P0.swap,neg_lo)
//         pk_fma(G.lo,P1)     ; pk_fma(G.hi,P1.swap,neg_hi)
//
// MODE 0: d_out = float[B*4096] (real parts); MODE 1: float2 interleaved.
template <int MODE>
__global__ __launch_bounds__(256)
void qsim_kernel(const float* __restrict__ x,
                 const float* __restrict__ input_params,
                 const float* __restrict__ weights,
                 float* __restrict__ out, long long out_elems) {
  const int b = blockIdx.x;
  const int tid = threadIdx.x;        // 0..255
  const int t4 = tid & 15;
  const int th = tid >> 4;

  __shared__ f2 lds[4096];            // 32 KB transpose buffer
  __shared__ f4 ctab[NQ];             // per-layer gate coefs (Gr,Gi,Hr,Hi)

  f2 s[16];
#pragma unroll
  for (int r = 0; r < 16; ++r) s[r] = (f2){0.f, 0.f};
  s[0] = (f2){tid == 0 ? 1.f : 0.f, 0.f};

  const float* xb = x + b * (NQ * LAYERS);

  // --- helpers ---
  auto cnotX = [&]() {                // control = tid bit0, target = reg bit3
    const bool odd = (tid & 1) != 0;
#pragma unroll
    for (int r = 0; r < 8; ++r) {
      const f2 a = s[r], c = s[r + 8];
      s[r]     = odd ? c : a;
      s[r + 8] = odd ? a : c;
    }
  };
  auto renames = [&]() {              // CNOTs (a,a+1)(a+1,a+2)(a+2,a+3) in-regs
#pragma unroll
    for (int w = 0; w < 3; ++w) {
      const int cm = 8 >> w, tm = cm >> 1;
#pragma unroll
      for (int r = 0; r < 16; ++r) {
        if ((r & cm) && !(r & tm)) {
          const int p = r | tm;
          const f2 t = s[r]; s[r] = s[p]; s[p] = t;
        }
      }
    }
  };
  auto gateP = [&](int wl, int m) {
    const f4 c = ctab[wl];            // ds_read_b128, uniform addr (broadcast)
    f2 G = {c.x, c.y};
    f2 H = {c.z, c.w};
#pragma unroll
    for (int r0 = 0; r0 < 16; ++r0) {
      if (r0 & m) continue;           // compile-time skip
      const int r1 = r0 | m;
      f2 P0 = s[r0], P1 = s[r1], T, U;
      // T = g*s0 - conj(h)*s1
      asm("v_pk_mul_f32 %0, %1, %2 op_sel:[0,0] op_sel_hi:[0,1]"
          : "=v"(T) : "v"(G), "v"(P0));
      asm("v_pk_fma_f32 %0, %1, %2, %0 op_sel:[1,1,0] op_sel_hi:[1,0,1] neg_lo:[1,0,0]"
          : "+v"(T) : "v"(G), "v"(P0));
      asm("v_pk_fma_f32 %0, %1, %2, %0 op_sel_hi:[0,1,1] neg_lo:[1,0,0] neg_hi:[1,0,0]"
          : "+v"(T) : "v"(H), "v"(P1));
      asm("v_pk_fma_f32 %0, %1, %2, %0 op_sel:[1,1,0] op_sel_hi:[1,0,1] neg_lo:[1,0,0]"
          : "+v"(T) : "v"(H), "v"(P1));
      // U = h*s0 + conj(g)*s1
      asm("v_pk_mul_f32 %0, %1, %2 op_sel:[0,0] op_sel_hi:[0,1]"
          : "=v"(U) : "v"(H), "v"(P0));
      asm("v_pk_fma_f32 %0, %1, %2, %0 op_sel:[1,1,0] op_sel_hi:[1,0,1] neg_lo:[1,0,0]"
          : "+v"(U) : "v"(H), "v"(P0));
      asm("v_pk_fma_f32 %0, %1, %2, %0 op_sel_hi:[0,1,1]"
          : "+v"(U) : "v"(G), "v"(P1));
      asm("v_pk_fma_f32 %0, %1, %2, %0 op_sel:[1,1,0] op_sel_hi:[1,0,1] neg_hi:[1,0,0]"
          : "+v"(U) : "v"(G), "v"(P1));
      s[r0] = T; s[r1] = U;
    }
  };
  auto transpose = [&]() {
#pragma unroll
    for (int r = 0; r < 16; ++r)
      lds[(r << 8) | (tid ^ (r * 0x11))] = s[r];
    __syncthreads();
    const int rb = (t4 << 8) | (t4 << 4) | (th ^ t4);
#pragma unroll
    for (int r = 0; r < 16; ++r)
      s[r] = lds[rb ^ (r << 4)];
    __syncthreads();
  };

#pragma unroll 1
  for (int l = 0; l < LAYERS; ++l) {
    // fused U_w = Rot_w * RY_w, computed once (threads 0..11), via LDS table
    if (tid < NQ) {
      const int idx = l * NQ + tid;
      const float a = input_params[idx] * xb[idx];
      float sa, ca; __sincosf(0.5f * a, &sa, &ca);
      const float phi = weights[idx * 3 + 0];
      const float thw = weights[idx * 3 + 1];
      const float om  = weights[idx * 3 + 2];
      float st, ct;    __sincosf(0.5f * thw, &st, &ct);
      float spp, cpp_; __sincosf(0.5f * (phi + om), &spp, &cpp_);
      float smm, cmm;  __sincosf(0.5f * (phi - om), &smm, &cmm);
      const float ar = ct * cpp_, ai = -ct * spp;
      const float br = st * cmm,  bi = -st * smm;
      ctab[tid] = (f4){ar * ca - br * sa,   // Gr
                       ai * ca + bi * sa,   // Gi
                       br * ca + ar * sa,   // Hr
                       bi * ca - ai * sa};  // Hi
    }
    if (l > 0) cnotX();                // CNOT(11,0) of previous layer
    __syncthreads();                   // ctab visible

    // Phase A (regs = w0..w3)
    gateP(0, 8); gateP(1, 4); gateP(2, 2); gateP(3, 1);
    renames();                         // CNOT(0,1)(1,2)(2,3)
    transpose();                       // -> layout B

    // Phase B (regs = w4..w7)
    gateP(4, 8);
    cnotX();                           // CNOT(3,4)
    gateP(5, 4); gateP(6, 2); gateP(7, 1);
    renames();                         // CNOT(4,5)(5,6)(6,7)
    transpose();                       // -> layout C

    // Phase C (regs = w8..w11)
    gateP(8, 8);
    cnotX();                           // CNOT(7,8)
    gateP(9, 4); gateP(10, 2); gateP(11, 1);
    renames();                         // CNOT(8,9)(9,10)(10,11)
    transpose();                       // -> layout A
  }

  cnotX();                             // final CNOT(11,0)

  // Store: amp = (r<<8) | tid -- reference flat order; fully coalesced.
  const long long base = ((long long)b << NQ) + tid;
  if (MODE == 0) {
#pragma unroll
    for (int r = 0; r < 16; ++r) {
      const long long idx = base + (r << 8);
      if (idx < out_elems) out[idx] = s[r].x;
    }
  } else {
    f2* ob = (f2*)out;
#pragma unroll
    for (int r = 0; r < 16; ++r) {
      const long long idx = base + (r << 8);
      if (2 * idx + 1 < out_elems) ob[idx] = s[r];
    }
  }
}

extern "C" void kernel_launch(void* const* d_in, const int* in_sizes, int n_in,
                              void* d_out, int out_size, void* d_ws, size_t ws_size,
                              hipStream_t stream) {
  const float* x  = (const float*)d_in[0];
  const float* ip = (const float*)d_in[1];
  const float* w  = (const float*)d_in[2];
  float* out = (float*)d_out;
  (void)in_sizes; (void)n_in; (void)d_ws; (void)ws_size;
  const long long total = (long long)BATCH << NQ;   // 16,777,216 amplitudes
  if ((long long)out_size == 2 * total) {
    qsim_kernel<1><<<BATCH, 256, 0, stream>>>(x, ip, w, out, (long long)out_size);
  } else {
    qsim_kernel<0><<<BATCH, 256, 0, stream>>>(x, ip, w, out, (long long)out_size);
  }
}